// Round 5
// baseline (586.962 us; speedup 1.0000x reference)
//
#include <hip/hip_runtime.h>
#include <hip/hip_bf16.h>
#include <stdint.h>

// ContrastiveLoss: N=8192, D=512 fp32 features, int labels {0,1}.
// out = mean_i [ (np_i * log(sum_exp_i) - sum_pos_i) / (np_i + 1e-8) ]
// R1: global_load_lds(16B) + XOR-swizzled LDS -> bank conflicts -> 0.
// R2: upper-triangle tiles only (2080), row+col scatter.
// R3: collision-free partial buffers replace device atomics.
// R4 post-mortem: latency-bound (all pipes <20%, occ 34%, 4 blocks/CU).
// R5: fp8-e4m3 staging+MFMA (x16 pre-scale; 10/256 epilogue scale):
//     halves staged bytes + LDS reads; LDS 34->16 KB (ldsF aliased into sA)
//     -> 8 blocks/CU = 32 waves/CU (hw max) for latency hiding.

#define N_ROWS 8192
#define DIMF 512   // floats per row
#define DIMB 512   // fp8 bytes per row
#define BKB 64     // K-tile in fp8 bytes
#define NB 64
#define NSLOT 64
#define SIM_SCALE 0.0390625f  // 10 / 256  (features pre-scaled by 16)

typedef float f32x4 __attribute__((ext_vector_type(4)));

__device__ static inline void gload_lds16(const uint8_t* g, uint8_t* l) {
    __builtin_amdgcn_global_load_lds(
        (const __attribute__((address_space(1))) unsigned int*)g,
        (__attribute__((address_space(3))) unsigned int*)l, 16, 0, 0);
}

// 4 waves/block, one row per wave: fp32 sumsq -> scale by 16/norm -> fp8 pack.
// Block 0 also counts label-1s and zeroes out[0].
__global__ __launch_bounds__(256) void norm_kernel(const float* __restrict__ x,
                                                   uint8_t* __restrict__ f8,
                                                   const int* __restrict__ lab,
                                                   int* __restrict__ cnt,
                                                   float* __restrict__ out) {
    __shared__ int shc[4];
    const int wave = threadIdx.x >> 6, t = threadIdx.x & 63;
    const int row = blockIdx.x * 4 + wave;
    const float4* xr = (const float4*)(x + (size_t)row * DIMF);
    float4 v0 = xr[2 * t];
    float4 v1 = xr[2 * t + 1];
    float ss = v0.x * v0.x + v0.y * v0.y + v0.z * v0.z + v0.w * v0.w +
               v1.x * v1.x + v1.y * v1.y + v1.z * v1.z + v1.w * v1.w;
#pragma unroll
    for (int off = 32; off >= 1; off >>= 1) ss += __shfl_xor(ss, off, 64);
    float s = 16.0f / fmaxf(sqrtf(ss), 1e-12f);
    int lo = 0, hi = 0;
    lo = __builtin_amdgcn_cvt_pk_fp8_f32(v0.x * s, v0.y * s, lo, false);
    lo = __builtin_amdgcn_cvt_pk_fp8_f32(v0.z * s, v0.w * s, lo, true);
    hi = __builtin_amdgcn_cvt_pk_fp8_f32(v1.x * s, v1.y * s, hi, false);
    hi = __builtin_amdgcn_cvt_pk_fp8_f32(v1.z * s, v1.w * s, hi, true);
    int2 pk;
    pk.x = lo;
    pk.y = hi;
    *(int2*)(f8 + (size_t)row * DIMB + 8 * t) = pk;

    if (blockIdx.x == 0) {
        int local = 0;
        for (int i = threadIdx.x; i < N_ROWS; i += 256) local += lab[i];
#pragma unroll
        for (int off = 32; off >= 1; off >>= 1) local += __shfl_xor(local, off, 64);
        if (t == 0) shc[wave] = local;
        __syncthreads();
        if (threadIdx.x == 0) {
            cnt[0] = shc[0] + shc[1] + shc[2] + shc[3];
            out[0] = 0.0f;
        }
    }
}

// 128x128 tile per block (4 waves 2x2, each 64x64 via 4x4 MFMA 16x16x32 fp8).
// BK=64B staged via global_load_lds(16B) into swizzled LDS:
//   row = 64B = 4 units of 16B; phys unit = logical ^ ((row>>1)&3).
// Staging instr: 64 lanes = 16 rows x 4 units; lane -> sub=lane>>2,
//   lu=(lane&3)^((sub>>1)&3); global src col-unit lu, phys slot lane.
// Frag reads: b64 at unit (2ks+(quad>>1))^((lrow>>1)&3) + (quad&1)*8 ->
//   uniform 4 touches/bank = LDS throughput floor.
__global__ __launch_bounds__(256, 8) void sim_kernel(const uint8_t* __restrict__ f8,
                                                     const int* __restrict__ lab,
                                                     float* __restrict__ PE,
                                                     float* __restrict__ PP) {
    __shared__ __align__(16) uint8_t smem[16384];
    uint8_t* sA = smem;          // 8 KB
    uint8_t* sB = smem + 8192;   // 8 KB
    float* ldsF = (float*)smem;  // 2 KB, aliased into sA after K-loop

    const int tblk = blockIdx.x;
    int bi = (int)(64.5f - sqrtf(64.5f * 64.5f - 2.0f * (float)tblk));
    while (bi * (129 - bi) / 2 > tblk) --bi;
    while ((bi + 1) * (128 - bi) / 2 <= tblk) ++bi;
    const int bj = bi + (tblk - bi * (129 - bi) / 2);
    const bool diag = (bi == bj);

    const int t = threadIdx.x;
    const int iBase = bi * 128, jBase = bj * 128;
    const int lane = t & 63, wave = t >> 6;
    const int wm = wave >> 1, wn = wave & 1;
    const int lrow = lane & 15, quad = lane >> 4;

    const int sub = lane >> 2;                     // row within 16-row chunk
    const int lu = (lane & 3) ^ ((sub >> 1) & 3);  // swizzled 16B col unit

    f32x4 acc[4][4] = {};

    for (int kk = 0; kk < DIMB; kk += BKB) {
#pragma unroll
        for (int c = 0; c < 2; ++c) {
            const int rbase = wave * 32 + c * 16;
            gload_lds16(f8 + (size_t)(iBase + rbase + sub) * DIMB + kk + lu * 16,
                        sA + rbase * 64);
            gload_lds16(f8 + (size_t)(jBase + rbase + sub) * DIMB + kk + lu * 16,
                        sB + rbase * 64);
        }
        __syncthreads();
#pragma unroll
        for (int ks = 0; ks < 2; ++ks) {
            const int su = ((2 * ks + (quad >> 1)) ^ ((lrow >> 1) & 3)) * 16 + (quad & 1) * 8;
            int64_t af[4], bfr[4];
#pragma unroll
            for (int m = 0; m < 4; ++m)
                af[m] = *(const int64_t*)(sA + (wm * 64 + m * 16 + lrow) * 64 + su);
#pragma unroll
            for (int n = 0; n < 4; ++n)
                bfr[n] = *(const int64_t*)(sB + (wn * 64 + n * 16 + lrow) * 64 + su);
#pragma unroll
            for (int m = 0; m < 4; ++m)
#pragma unroll
                for (int n = 0; n < 4; ++n)
                    acc[m][n] = __builtin_amdgcn_mfma_f32_16x16x32_fp8_fp8(
                        af[m], bfr[n], acc[m][n], 0, 0, 0);
        }
        __syncthreads();
    }

    // sA no longer needed; alias its head as the fold buffer.
    ldsF[t] = 0.0f;
    ldsF[t + 256] = 0.0f;
    __syncthreads();

    // Epilogue. C/D layout: col = lane&15, row = quad*4 + reg (m89-verified,
    // dtype-independent).
    int labj[4];
#pragma unroll
    for (int n = 0; n < 4; ++n) labj[n] = lab[jBase + wn * 64 + n * 16 + lrow];

    if (diag) {
#pragma unroll
        for (int m = 0; m < 4; ++m) {
#pragma unroll
            for (int e = 0; e < 4; ++e) {
                int r = wm * 64 + m * 16 + quad * 4 + e;
                int i = iBase + r;
                int labi = lab[i];
                float se = 0.0f, sp = 0.0f;
#pragma unroll
                for (int n = 0; n < 4; ++n) {
                    int j = jBase + wn * 64 + n * 16 + lrow;
                    float sim = acc[m][n][e] * SIM_SCALE;
                    if (j != i) {
                        se += __expf(sim);
                        if (labj[n] == labi) sp += sim;
                    }
                }
#pragma unroll
                for (int off = 8; off >= 1; off >>= 1) {
                    se += __shfl_xor(se, off, 16);
                    sp += __shfl_xor(sp, off, 16);
                }
                if (lrow == 0) {
                    atomicAdd(&ldsF[r], se);  // ds_add: fold wn wave pair
                    atomicAdd(&ldsF[128 + r], sp);
                }
            }
        }
    } else {
        float sec[4] = {0, 0, 0, 0}, spc[4] = {0, 0, 0, 0};
#pragma unroll
        for (int m = 0; m < 4; ++m) {
#pragma unroll
            for (int e = 0; e < 4; ++e) {
                int r = wm * 64 + m * 16 + quad * 4 + e;
                int labi = lab[iBase + r];
                float se = 0.0f, sp = 0.0f;
#pragma unroll
                for (int n = 0; n < 4; ++n) {
                    float sim = acc[m][n][e] * SIM_SCALE;
                    float ex = __expf(sim);
                    se += ex;
                    sec[n] += ex;
                    if (labj[n] == labi) {
                        sp += sim;
                        spc[n] += sim;
                    }
                }
#pragma unroll
                for (int off = 8; off >= 1; off >>= 1) {
                    se += __shfl_xor(se, off, 16);
                    sp += __shfl_xor(sp, off, 16);
                }
                if (lrow == 0) {
                    atomicAdd(&ldsF[r], se);
                    atomicAdd(&ldsF[128 + r], sp);
                }
            }
        }
#pragma unroll
        for (int n = 0; n < 4; ++n) {
            int c = wn * 64 + n * 16 + lrow;
            atomicAdd(&ldsF[256 + c], sec[n]);
            atomicAdd(&ldsF[384 + c], spc[n]);
        }
    }
    __syncthreads();

    // Collision-free slot stores: rows -> slot bj, cols -> slot bi.
    if (t < 128) {
        PE[(size_t)bj * N_ROWS + iBase + t] = ldsF[t];
        PP[(size_t)bj * N_ROWS + iBase + t] = ldsF[128 + t];
    } else if (!diag) {
        int c = t - 128;
        PE[(size_t)bi * N_ROWS + jBase + c] = ldsF[256 + c];
        PP[(size_t)bi * N_ROWS + jBase + c] = ldsF[384 + c];
    }
}

// 32 blocks x 256 rows: sum 64 slots, per-row loss, atomicAdd mean into out.
__global__ __launch_bounds__(256) void final_kernel(const float* __restrict__ PE,
                                                    const float* __restrict__ PP,
                                                    const int* __restrict__ lab,
                                                    const int* __restrict__ cnt,
                                                    float* __restrict__ out) {
    const int i = blockIdx.x * 256 + threadIdx.x;
    float se = 0.0f, sp = 0.0f;
#pragma unroll 8
    for (int s = 0; s < NSLOT; ++s) {
        se += PE[(size_t)s * N_ROWS + i];
        sp += PP[(size_t)s * N_ROWS + i];
    }
    const float c1 = (float)cnt[0];
    float np = (lab[i] ? c1 : (float)N_ROWS - c1) - 1.0f;
    float local = (np * __logf(se) - sp) / (np + 1e-8f);
    __shared__ float sh[4];
    int lane = threadIdx.x & 63, w = threadIdx.x >> 6;
#pragma unroll
    for (int off = 32; off >= 1; off >>= 1) local += __shfl_xor(local, off, 64);
    if (lane == 0) sh[w] = local;
    __syncthreads();
    if (threadIdx.x == 0)
        atomicAdd(out, (sh[0] + sh[1] + sh[2] + sh[3]) * (1.0f / (float)N_ROWS));
}

extern "C" void kernel_launch(void* const* d_in, const int* in_sizes, int n_in,
                              void* d_out, int out_size, void* d_ws, size_t ws_size,
                              hipStream_t stream) {
    const float* features = (const float*)d_in[0];
    const int* labels = (const int*)d_in[1];
    float* out = (float*)d_out;

    char* ws = (char*)d_ws;
    uint8_t* f8 = (uint8_t*)ws;                              // 4 MiB
    float* PE = (float*)(ws + (size_t)N_ROWS * DIMB);        // 2 MiB
    float* PP = PE + (size_t)NSLOT * N_ROWS;                 // 2 MiB
    int* cnt = (int*)(PP + (size_t)NSLOT * N_ROWS);          // 4 B

    norm_kernel<<<N_ROWS / 4, 256, 0, stream>>>(features, f8, labels, cnt, out);
    sim_kernel<<<NB * (NB + 1) / 2, 256, 0, stream>>>(f8, labels, PE, PP);
    final_kernel<<<N_ROWS / 256, 256, 0, stream>>>(PE, PP, labels, cnt, out);
}

// Round 6
// 166.355 us; speedup vs baseline: 3.5284x; 3.5284x over previous
//
#include <hip/hip_runtime.h>
#include <hip/hip_bf16.h>
#include <stdint.h>

// ContrastiveLoss: N=8192, D=512 fp32 features, int labels {0,1}.
// out = mean_i [ (np_i * log(sum_exp_i) - sum_pos_i) / (np_i + 1e-8) ]
// R1: global_load_lds(16B) + XOR-swizzled LDS -> bank conflicts -> 0.
// R2: upper-triangle tiles only (2080), row+col scatter.
// R3: collision-free partial buffers replace device atomics.
// R5 post-mortem: launch_bounds(256,8) spilled acc (64 VGPR) to scratch ->
//     1.9 GB/dispatch scratch traffic; b64 frag reads = 2x bank touches.
// R6: fp8 kept; (256,4) -> no spill; k pre-permuted per 128B row tile in
//     norm ([ks][q]->[q][ks], dot-invariant since A,B permuted identically)
//     so frag reads are b128 (R2-proven 0-conflict geometry), each feeding
//     2 MFMAs; BK=128B -> 4 K-iters, half the barrier drains. LDS 32 KB.

#define N_ROWS 8192
#define DIMF 512   // floats per row
#define DIMB 512   // fp8 bytes per row
#define BKB 128    // K-tile bytes
#define NB 64
#define NSLOT 64
#define SIM_SCALE 0.0390625f  // 10 / 256  (features pre-scaled by 16)

typedef float f32x4 __attribute__((ext_vector_type(4)));
typedef int64_t i64x2 __attribute__((ext_vector_type(2)));

__device__ static inline void gload_lds16(const uint8_t* g, uint8_t* l) {
    __builtin_amdgcn_global_load_lds(
        (const __attribute__((address_space(1))) unsigned int*)g,
        (__attribute__((address_space(3))) unsigned int*)l, 16, 0, 0);
}

// 4 waves/block, one row per wave: fp32 sumsq -> scale by 16/norm -> fp8,
// stored k-permuted: within each 128B tile, byte group (ks,q) -> q*32+ks*8.
// Lane t owns orig k = 8t..8t+7 (one group: ks=(t&15)>>2, q=t&3).
// Block 0 also counts label-1s and zeroes out[0].
__global__ __launch_bounds__(256) void norm_kernel(const float* __restrict__ x,
                                                   uint8_t* __restrict__ f8,
                                                   const int* __restrict__ lab,
                                                   int* __restrict__ cnt,
                                                   float* __restrict__ out) {
    __shared__ int shc[4];
    const int wave = threadIdx.x >> 6, t = threadIdx.x & 63;
    const int row = blockIdx.x * 4 + wave;
    const float4* xr = (const float4*)(x + (size_t)row * DIMF);
    float4 v0 = xr[2 * t];
    float4 v1 = xr[2 * t + 1];
    float ss = v0.x * v0.x + v0.y * v0.y + v0.z * v0.z + v0.w * v0.w +
               v1.x * v1.x + v1.y * v1.y + v1.z * v1.z + v1.w * v1.w;
#pragma unroll
    for (int off = 32; off >= 1; off >>= 1) ss += __shfl_xor(ss, off, 64);
    float s = 16.0f / fmaxf(sqrtf(ss), 1e-12f);
    int lo = 0, hi = 0;
    lo = __builtin_amdgcn_cvt_pk_fp8_f32(v0.x * s, v0.y * s, lo, false);
    lo = __builtin_amdgcn_cvt_pk_fp8_f32(v0.z * s, v0.w * s, lo, true);
    hi = __builtin_amdgcn_cvt_pk_fp8_f32(v1.x * s, v1.y * s, hi, false);
    hi = __builtin_amdgcn_cvt_pk_fp8_f32(v1.z * s, v1.w * s, hi, true);
    int2 pk;
    pk.x = lo;
    pk.y = hi;
    const int pos = (t >> 4) * 128 + (t & 3) * 32 + ((t >> 2) & 3) * 8;
    *(int2*)(f8 + (size_t)row * DIMB + pos) = pk;

    if (blockIdx.x == 0) {
        int local = 0;
        for (int i = threadIdx.x; i < N_ROWS; i += 256) local += lab[i];
#pragma unroll
        for (int off = 32; off >= 1; off >>= 1) local += __shfl_xor(local, off, 64);
        if (t == 0) shc[wave] = local;
        __syncthreads();
        if (threadIdx.x == 0) {
            cnt[0] = shc[0] + shc[1] + shc[2] + shc[3];
            out[0] = 0.0f;
        }
    }
}

// 128x128 tile per block (4 waves 2x2, each 64x64 via 4x4 MFMA 16x16x32 fp8).
// BK=128B staged via global_load_lds(16B) into XOR-swizzled LDS rows of 128B
// (8 x 16B units; phys unit = logical ^ (row&7)) -- R2-proven geometry.
// Frag reads: b128 at logical unit 2*quad+pair -> two k-step frags per read.
__global__ __launch_bounds__(256, 4) void sim_kernel(const uint8_t* __restrict__ f8,
                                                     const int* __restrict__ lab,
                                                     float* __restrict__ PE,
                                                     float* __restrict__ PP) {
    __shared__ __align__(16) uint8_t smem[32768];
    uint8_t* sA = smem;          // 16 KB: 128 rows x 128 B
    uint8_t* sB = smem + 16384;  // 16 KB
    float* ldsF = (float*)smem;  // 2 KB, aliased into sA after K-loop

    const int tblk = blockIdx.x;
    int bi = (int)(64.5f - sqrtf(64.5f * 64.5f - 2.0f * (float)tblk));
    while (bi * (129 - bi) / 2 > tblk) --bi;
    while ((bi + 1) * (128 - bi) / 2 <= tblk) ++bi;
    const int bj = bi + (tblk - bi * (129 - bi) / 2);
    const bool diag = (bi == bj);

    const int t = threadIdx.x;
    const int iBase = bi * 128, jBase = bj * 128;
    const int lane = t & 63, wave = t >> 6;
    const int wm = wave >> 1, wn = wave & 1;
    const int lrow = lane & 15, quad = lane >> 4;

    // staging: 64 lanes = 8 rows x 8 phys units; src logical unit = phys^row
    const int sub = lane >> 3;        // row within 8-row chunk
    const int lu = (lane & 7) ^ sub;  // swizzled 16B source unit

    f32x4 acc[4][4] = {};

    for (int kk = 0; kk < DIMB; kk += BKB) {
#pragma unroll
        for (int c = 0; c < 4; ++c) {
            const int rbase = wave * 32 + c * 8;
            gload_lds16(f8 + (size_t)(iBase + rbase + sub) * DIMB + kk + lu * 16,
                        sA + rbase * 128);
            gload_lds16(f8 + (size_t)(jBase + rbase + sub) * DIMB + kk + lu * 16,
                        sB + rbase * 128);
        }
        __syncthreads();
#pragma unroll
        for (int p = 0; p < 2; ++p) {
            const int su = (((quad << 1) + p) ^ (lrow & 7)) << 4;
            i64x2 af[4], bfr[4];
#pragma unroll
            for (int m = 0; m < 4; ++m)
                af[m] = *(const i64x2*)(sA + (wm * 64 + m * 16 + lrow) * 128 + su);
#pragma unroll
            for (int n = 0; n < 4; ++n)
                bfr[n] = *(const i64x2*)(sB + (wn * 64 + n * 16 + lrow) * 128 + su);
#pragma unroll
            for (int m = 0; m < 4; ++m)
#pragma unroll
                for (int n = 0; n < 4; ++n) {
                    acc[m][n] = __builtin_amdgcn_mfma_f32_16x16x32_fp8_fp8(
                        af[m].x, bfr[n].x, acc[m][n], 0, 0, 0);
                    acc[m][n] = __builtin_amdgcn_mfma_f32_16x16x32_fp8_fp8(
                        af[m].y, bfr[n].y, acc[m][n], 0, 0, 0);
                }
        }
        __syncthreads();
    }

    ldsF[t] = 0.0f;
    ldsF[t + 256] = 0.0f;
    __syncthreads();

    // Epilogue. C/D layout: col = lane&15, row = quad*4 + reg (m89-verified).
    int labj[4];
#pragma unroll
    for (int n = 0; n < 4; ++n) labj[n] = lab[jBase + wn * 64 + n * 16 + lrow];

    if (diag) {
#pragma unroll
        for (int m = 0; m < 4; ++m) {
#pragma unroll
            for (int e = 0; e < 4; ++e) {
                int r = wm * 64 + m * 16 + quad * 4 + e;
                int i = iBase + r;
                int labi = lab[i];
                float se = 0.0f, sp = 0.0f;
#pragma unroll
                for (int n = 0; n < 4; ++n) {
                    int j = jBase + wn * 64 + n * 16 + lrow;
                    float sim = acc[m][n][e] * SIM_SCALE;
                    if (j != i) {
                        se += __expf(sim);
                        if (labj[n] == labi) sp += sim;
                    }
                }
#pragma unroll
                for (int off = 8; off >= 1; off >>= 1) {
                    se += __shfl_xor(se, off, 16);
                    sp += __shfl_xor(sp, off, 16);
                }
                if (lrow == 0) {
                    atomicAdd(&ldsF[r], se);  // ds_add: fold wn wave pair
                    atomicAdd(&ldsF[128 + r], sp);
                }
            }
        }
    } else {
        float sec[4] = {0, 0, 0, 0}, spc[4] = {0, 0, 0, 0};
#pragma unroll
        for (int m = 0; m < 4; ++m) {
#pragma unroll
            for (int e = 0; e < 4; ++e) {
                int r = wm * 64 + m * 16 + quad * 4 + e;
                int labi = lab[iBase + r];
                float se = 0.0f, sp = 0.0f;
#pragma unroll
                for (int n = 0; n < 4; ++n) {
                    float sim = acc[m][n][e] * SIM_SCALE;
                    float ex = __expf(sim);
                    se += ex;
                    sec[n] += ex;
                    if (labj[n] == labi) {
                        sp += sim;
                        spc[n] += sim;
                    }
                }
#pragma unroll
                for (int off = 8; off >= 1; off >>= 1) {
                    se += __shfl_xor(se, off, 16);
                    sp += __shfl_xor(sp, off, 16);
                }
                if (lrow == 0) {
                    atomicAdd(&ldsF[r], se);
                    atomicAdd(&ldsF[128 + r], sp);
                }
            }
        }
#pragma unroll
        for (int n = 0; n < 4; ++n) {
            int c = wn * 64 + n * 16 + lrow;
            atomicAdd(&ldsF[256 + c], sec[n]);
            atomicAdd(&ldsF[384 + c], spc[n]);
        }
    }
    __syncthreads();

    // Collision-free slot stores: rows -> slot bj, cols -> slot bi.
    if (t < 128) {
        PE[(size_t)bj * N_ROWS + iBase + t] = ldsF[t];
        PP[(size_t)bj * N_ROWS + iBase + t] = ldsF[128 + t];
    } else if (!diag) {
        int c = t - 128;
        PE[(size_t)bi * N_ROWS + jBase + c] = ldsF[256 + c];
        PP[(size_t)bi * N_ROWS + jBase + c] = ldsF[384 + c];
    }
}

// 32 blocks x 256 rows: sum 64 slots, per-row loss, atomicAdd mean into out.
__global__ __launch_bounds__(256) void final_kernel(const float* __restrict__ PE,
                                                    const float* __restrict__ PP,
                                                    const int* __restrict__ lab,
                                                    const int* __restrict__ cnt,
                                                    float* __restrict__ out) {
    const int i = blockIdx.x * 256 + threadIdx.x;
    float se = 0.0f, sp = 0.0f;
#pragma unroll 8
    for (int s = 0; s < NSLOT; ++s) {
        se += PE[(size_t)s * N_ROWS + i];
        sp += PP[(size_t)s * N_ROWS + i];
    }
    const float c1 = (float)cnt[0];
    float np = (lab[i] ? c1 : (float)N_ROWS - c1) - 1.0f;
    float local = (np * __logf(se) - sp) / (np + 1e-8f);
    __shared__ float sh[4];
    int lane = threadIdx.x & 63, w = threadIdx.x >> 6;
#pragma unroll
    for (int off = 32; off >= 1; off >>= 1) local += __shfl_xor(local, off, 64);
    if (lane == 0) sh[w] = local;
    __syncthreads();
    if (threadIdx.x == 0)
        atomicAdd(out, (sh[0] + sh[1] + sh[2] + sh[3]) * (1.0f / (float)N_ROWS));
}

extern "C" void kernel_launch(void* const* d_in, const int* in_sizes, int n_in,
                              void* d_out, int out_size, void* d_ws, size_t ws_size,
                              hipStream_t stream) {
    const float* features = (const float*)d_in[0];
    const int* labels = (const int*)d_in[1];
    float* out = (float*)d_out;

    char* ws = (char*)d_ws;
    uint8_t* f8 = (uint8_t*)ws;                              // 4 MiB
    float* PE = (float*)(ws + (size_t)N_ROWS * DIMB);        // 2 MiB
    float* PP = PE + (size_t)NSLOT * N_ROWS;                 // 2 MiB
    int* cnt = (int*)(PP + (size_t)NSLOT * N_ROWS);          // 4 B

    norm_kernel<<<N_ROWS / 4, 256, 0, stream>>>(features, f8, labels, cnt, out);
    sim_kernel<<<NB * (NB + 1) / 2, 256, 0, stream>>>(f8, labels, PE, PP);
    final_kernel<<<N_ROWS / 256, 256, 0, stream>>>(PE, PP, labels, cnt, out);
}

// Round 7
// 122.677 us; speedup vs baseline: 4.7846x; 1.3560x over previous
//
#include <hip/hip_runtime.h>
#include <hip/hip_bf16.h>
#include <stdint.h>

// ContrastiveLoss: N=8192, D=512 fp32 features, int labels {0,1}.
// out = mean_i [ (np_i * log(sum_exp_i) - sum_pos_i) / (np_i + 1e-8) ]
// R1: global_load_lds(16B) + XOR-swizzled LDS (conflict-free b128 reads).
// R2: upper-triangle tiles only (2080), row+col scatter.
// R3: collision-free partial buffers replace device atomics.
// R5: fp8-e4m3 (x16 pre-scale, k pre-permuted in norm so A/B dots invariant).
// R6 post-mortem: L2-thrash: FETCH 71 MB vs 4 MB unique; 1.7 TB/s ~ dur.
// R7: (a) XCD swizzle tblk=(b&7)*260+(b>>3) -> contiguous triangle run per
//     XCD (A-strip shared by ~60 consecutive blocks, B reuse ~ L2 size);
//     (b) register-only epilogue: butterfly sums -> direct stores into 128
//     slots (rows->slot 2bj+wn, cols->slot 2bi+wm; diag rows only) -- kills
//     2 barriers + LDS fold per block. Coverage: slot s region r: r<=s/2
//     row-writer (r,s/2), r>s/2 col-writer (s/2,r); exactly once each.

#define N_ROWS 8192
#define DIMF 512
#define DIMB 512
#define BKB 128
#define NB 64
#define NSLOT 128
#define SIM_SCALE 0.0390625f  // 10 / 256  (features pre-scaled by 16)

typedef float f32x4 __attribute__((ext_vector_type(4)));
typedef int64_t i64x2 __attribute__((ext_vector_type(2)));

__device__ static inline void gload_lds16(const uint8_t* g, uint8_t* l) {
    __builtin_amdgcn_global_load_lds(
        (const __attribute__((address_space(1))) unsigned int*)g,
        (__attribute__((address_space(3))) unsigned int*)l, 16, 0, 0);
}

// 4 waves/block, one row per wave: fp32 sumsq -> scale by 16/norm -> fp8,
// stored k-permuted per 128B tile: (ks,q) -> q*32+ks*8 (dot-invariant).
// Block 0 also counts label-1s and zeroes out[0].
__global__ __launch_bounds__(256) void norm_kernel(const float* __restrict__ x,
                                                   uint8_t* __restrict__ f8,
                                                   const int* __restrict__ lab,
                                                   int* __restrict__ cnt,
                                                   float* __restrict__ out) {
    __shared__ int shc[4];
    const int wave = threadIdx.x >> 6, t = threadIdx.x & 63;
    const int row = blockIdx.x * 4 + wave;
    const float4* xr = (const float4*)(x + (size_t)row * DIMF);
    float4 v0 = xr[2 * t];
    float4 v1 = xr[2 * t + 1];
    float ss = v0.x * v0.x + v0.y * v0.y + v0.z * v0.z + v0.w * v0.w +
               v1.x * v1.x + v1.y * v1.y + v1.z * v1.z + v1.w * v1.w;
#pragma unroll
    for (int off = 32; off >= 1; off >>= 1) ss += __shfl_xor(ss, off, 64);
    float s = 16.0f / fmaxf(sqrtf(ss), 1e-12f);
    int lo = 0, hi = 0;
    lo = __builtin_amdgcn_cvt_pk_fp8_f32(v0.x * s, v0.y * s, lo, false);
    lo = __builtin_amdgcn_cvt_pk_fp8_f32(v0.z * s, v0.w * s, lo, true);
    hi = __builtin_amdgcn_cvt_pk_fp8_f32(v1.x * s, v1.y * s, hi, false);
    hi = __builtin_amdgcn_cvt_pk_fp8_f32(v1.z * s, v1.w * s, hi, true);
    int2 pk;
    pk.x = lo;
    pk.y = hi;
    const int pos = (t >> 4) * 128 + (t & 3) * 32 + ((t >> 2) & 3) * 8;
    *(int2*)(f8 + (size_t)row * DIMB + pos) = pk;

    if (blockIdx.x == 0) {
        int local = 0;
        for (int i = threadIdx.x; i < N_ROWS; i += 256) local += lab[i];
#pragma unroll
        for (int off = 32; off >= 1; off >>= 1) local += __shfl_xor(local, off, 64);
        if (t == 0) shc[wave] = local;
        __syncthreads();
        if (threadIdx.x == 0) {
            cnt[0] = shc[0] + shc[1] + shc[2] + shc[3];
            out[0] = 0.0f;
        }
    }
}

// 128x128 tile/block (4 waves 2x2, each 64x64 via 4x4 MFMA 16x16x32 fp8).
// BK=128B via global_load_lds(16B) into XOR-swizzled LDS rows of 128B.
__global__ __launch_bounds__(256, 4) void sim_kernel(const uint8_t* __restrict__ f8,
                                                     const int* __restrict__ lab,
                                                     float* __restrict__ PE,
                                                     float* __restrict__ PP) {
    __shared__ __align__(16) uint8_t smem[32768];
    uint8_t* sA = smem;
    uint8_t* sB = smem + 16384;

    // XCD-locality swizzle (2080 = 8 * 260); decode upper-triangle index.
    const int tblk = (blockIdx.x & 7) * 260 + (blockIdx.x >> 3);
    int bi = (int)(64.5f - sqrtf(64.5f * 64.5f - 2.0f * (float)tblk));
    while (bi * (129 - bi) / 2 > tblk) --bi;
    while ((bi + 1) * (128 - bi) / 2 <= tblk) ++bi;
    const int bj = bi + (tblk - bi * (129 - bi) / 2);
    const bool diag = (bi == bj);

    const int t = threadIdx.x;
    const int iBase = bi * 128, jBase = bj * 128;
    const int lane = t & 63, wave = t >> 6;
    const int wm = wave >> 1, wn = wave & 1;
    const int lrow = lane & 15, quad = lane >> 4;

    const int sub = lane >> 3;        // row within 8-row staging chunk
    const int lu = (lane & 7) ^ sub;  // swizzled 16B source unit

    f32x4 acc[4][4] = {};

    for (int kk = 0; kk < DIMB; kk += BKB) {
#pragma unroll
        for (int c = 0; c < 4; ++c) {
            const int rbase = wave * 32 + c * 8;
            gload_lds16(f8 + (size_t)(iBase + rbase + sub) * DIMB + kk + lu * 16,
                        sA + rbase * 128);
            gload_lds16(f8 + (size_t)(jBase + rbase + sub) * DIMB + kk + lu * 16,
                        sB + rbase * 128);
        }
        __syncthreads();
#pragma unroll
        for (int p = 0; p < 2; ++p) {
            const int su = (((quad << 1) + p) ^ (lrow & 7)) << 4;
            i64x2 af[4], bfr[4];
#pragma unroll
            for (int m = 0; m < 4; ++m)
                af[m] = *(const i64x2*)(sA + (wm * 64 + m * 16 + lrow) * 128 + su);
#pragma unroll
            for (int n = 0; n < 4; ++n)
                bfr[n] = *(const i64x2*)(sB + (wn * 64 + n * 16 + lrow) * 128 + su);
#pragma unroll
            for (int m = 0; m < 4; ++m)
#pragma unroll
                for (int n = 0; n < 4; ++n) {
                    acc[m][n] = __builtin_amdgcn_mfma_f32_16x16x32_fp8_fp8(
                        af[m].x, bfr[n].x, acc[m][n], 0, 0, 0);
                    acc[m][n] = __builtin_amdgcn_mfma_f32_16x16x32_fp8_fp8(
                        af[m].y, bfr[n].y, acc[m][n], 0, 0, 0);
                }
        }
        __syncthreads();
    }

    // Register-only epilogue. C/D layout: col=lane&15, row=quad*4+reg.
    // Butterfly xor-reduce leaves the sum in ALL lanes -> direct stores.
    int labj[4];
#pragma unroll
    for (int n = 0; n < 4; ++n) labj[n] = lab[jBase + wn * 64 + n * 16 + lrow];

    const int slotR = 2 * bj + wn;  // rows of iBase
    const int slotC = 2 * bi + wm;  // cols of jBase
    float sec[4] = {0, 0, 0, 0}, spc[4] = {0, 0, 0, 0};

#pragma unroll
    for (int m = 0; m < 4; ++m) {
        float rE[4], rP[4];
#pragma unroll
        for (int e = 0; e < 4; ++e) {
            const int r = wm * 64 + m * 16 + quad * 4 + e;
            const int i = iBase + r;
            const int labi = lab[i];
            float se = 0.0f, sp = 0.0f;
            if (diag) {
#pragma unroll
                for (int n = 0; n < 4; ++n) {
                    const int j = jBase + wn * 64 + n * 16 + lrow;
                    const float sim = acc[m][n][e] * SIM_SCALE;
                    if (j != i) {
                        se += __expf(sim);
                        if (labj[n] == labi) sp += sim;
                    }
                }
            } else {
#pragma unroll
                for (int n = 0; n < 4; ++n) {
                    const float sim = acc[m][n][e] * SIM_SCALE;
                    const float ex = __expf(sim);
                    se += ex;
                    sec[n] += ex;
                    if (labj[n] == labi) {
                        sp += sim;
                        spc[n] += sim;
                    }
                }
            }
#pragma unroll
            for (int off = 8; off >= 1; off >>= 1) {
                se += __shfl_xor(se, off, 16);
                sp += __shfl_xor(sp, off, 16);
            }
            rE[e] = se;
            rP[e] = sp;
        }
        if (lrow == 0) {
            const size_t o = (size_t)slotR * N_ROWS + iBase + wm * 64 + m * 16 + quad * 4;
            float4 vE = {rE[0], rE[1], rE[2], rE[3]};
            float4 vP = {rP[0], rP[1], rP[2], rP[3]};
            *(float4*)&PE[o] = vE;
            *(float4*)&PP[o] = vP;
        }
    }

    if (!diag) {
#pragma unroll
        for (int n = 0; n < 4; ++n) {
            sec[n] += __shfl_xor(sec[n], 16, 64);
            sec[n] += __shfl_xor(sec[n], 32, 64);
            spc[n] += __shfl_xor(spc[n], 16, 64);
            spc[n] += __shfl_xor(spc[n], 32, 64);
        }
        if (quad == 0) {
#pragma unroll
            for (int n = 0; n < 4; ++n) {
                const size_t o = (size_t)slotC * N_ROWS + jBase + wn * 64 + n * 16 + lrow;
                PE[o] = sec[n];
                PP[o] = spc[n];
            }
        }
    }
}

// 32 blocks x 256 rows: sum 128 slots, per-row loss, atomicAdd mean into out.
__global__ __launch_bounds__(256) void final_kernel(const float* __restrict__ PE,
                                                    const float* __restrict__ PP,
                                                    const int* __restrict__ lab,
                                                    const int* __restrict__ cnt,
                                                    float* __restrict__ out) {
    const int i = blockIdx.x * 256 + threadIdx.x;
    float se = 0.0f, sp = 0.0f;
#pragma unroll 8
    for (int s = 0; s < NSLOT; ++s) {
        se += PE[(size_t)s * N_ROWS + i];
        sp += PP[(size_t)s * N_ROWS + i];
    }
    const float c1 = (float)cnt[0];
    float np = (lab[i] ? c1 : (float)N_ROWS - c1) - 1.0f;
    float local = (np * __logf(se) - sp) / (np + 1e-8f);
    __shared__ float sh[4];
    int lane = threadIdx.x & 63, w = threadIdx.x >> 6;
#pragma unroll
    for (int off = 32; off >= 1; off >>= 1) local += __shfl_xor(local, off, 64);
    if (lane == 0) sh[w] = local;
    __syncthreads();
    if (threadIdx.x == 0)
        atomicAdd(out, (sh[0] + sh[1] + sh[2] + sh[3]) * (1.0f / (float)N_ROWS));
}

extern "C" void kernel_launch(void* const* d_in, const int* in_sizes, int n_in,
                              void* d_out, int out_size, void* d_ws, size_t ws_size,
                              hipStream_t stream) {
    const float* features = (const float*)d_in[0];
    const int* labels = (const int*)d_in[1];
    float* out = (float*)d_out;

    char* ws = (char*)d_ws;
    uint8_t* f8 = (uint8_t*)ws;                              // 4 MiB
    float* PE = (float*)(ws + (size_t)N_ROWS * DIMB);        // 4 MiB
    float* PP = PE + (size_t)NSLOT * N_ROWS;                 // 4 MiB
    int* cnt = (int*)(PP + (size_t)NSLOT * N_ROWS);          // 4 B

    norm_kernel<<<N_ROWS / 4, 256, 0, stream>>>(features, f8, labels, cnt, out);
    sim_kernel<<<NB * (NB + 1) / 2, 256, 0, stream>>>(f8, labels, PE, PP);
    final_kernel<<<N_ROWS / 256, 256, 0, stream>>>(PE, PP, labels, cnt, out);
}